// Round 9
// baseline (74.089 us; speedup 1.0000x reference)
//
#include <hip/hip_runtime.h>
#include <cstdint>
#include <cstddef>

// HardDetectionModule: per-element detect = is_depth_wise_max & is_local_max & is_not_edge
// batch: (B=2, C=512, H=192, W=256) float32, row-major.
// Output: same shape, int32 0/1 (reference returns bool -> harness reads int32).
//
// R6 -> R8: 60.1 us at 5.4 TB/s effective (86% of copy ceiling). Now 4 columns
// per thread via dwordx4 loads / NT dwordx4 zero-stores (16B/lane sweet spot,
// 1 KiB per wave mem op). 1024-thread blocks: 16 waves x 32-channel segments.
// (R7 failed to compile: __builtin_nontemporal_store needs a clang vector
// type, not HIP's int4 class -> use ext_vector_type.)

namespace {

constexpr int Bn = 2;
constexpr int Cn = 512;
constexpr int Hn = 192;
constexpr int Wn = 256;
constexpr int CH  = Hn * Wn;         // channel stride in elements (49152)
constexpr int SEG = 16;              // wave-segments per column
constexpr int CPS = Cn / SEG;        // 32 channels per segment
constexpr int NGROUPS = SEG;         // one 32-channel mask group per segment

typedef float f32x4 __attribute__((ext_vector_type(4)));
typedef int   i32x4 __attribute__((ext_vector_type(4)));

__global__ __launch_bounds__(1024)
void hard_detect_kernel(const float* __restrict__ in, int* __restrict__ out) {
    const int tid = threadIdx.x & 63;            // lane 0..63
    const int s   = threadIdx.x >> 6;            // segment (wave) 0..15
    const int j0  = tid * 4;                     // first of this lane's 4 columns
    const int i   = blockIdx.y;                  // 0..191
    const int b   = blockIdx.z;                  // 0..1

    // [group][lane], 16B per lane.
    __shared__ uint4  smask[NGROUPS][64];
    __shared__ float4 smaxv[NGROUPS][64];

    // element index of (b, c=0, i, j0)
    const size_t base = ((size_t)b * Cn * Hn + (size_t)i) * Wn + (size_t)j0;

    // ---- Pass 1: each wave streams its 32-channel segment of 4 columns/lane.
    //  - per-column running max M0..M3
    //  - zero the output (mandatory full write; doubles as init), 16B NT store
    //  - bitmask of "v == running max" per column (mask resets when a strictly
    //    larger value appears) + running max at segment end. A segment's mask
    //    is valid iff its end-max equals the final column max; surviving bits
    //    mark exactly the channels equal to it (ties exact).
    float M0 = -__builtin_inff(), M1 = M0, M2 = M0, M3 = M0;
    uint32_t m0 = 0u, m1 = 0u, m2 = 0u, m3 = 0u;
    #pragma unroll
    for (int k = 0; k < CPS; ++k) {
        const int c = s * CPS + k;
        const size_t idx = base + (size_t)c * (size_t)CH;
        const f32x4 v = *reinterpret_cast<const f32x4*>(&in[idx]);
        const i32x4 z = {0, 0, 0, 0};
        __builtin_nontemporal_store(z, reinterpret_cast<i32x4*>(&out[idx]));
        if (v.x > M0) { M0 = v.x; m0 = (1u << k); } else if (v.x == M0) { m0 |= (1u << k); }
        if (v.y > M1) { M1 = v.y; m1 = (1u << k); } else if (v.y == M1) { m1 |= (1u << k); }
        if (v.z > M2) { M2 = v.z; m2 = (1u << k); } else if (v.z == M2) { m2 |= (1u << k); }
        if (v.w > M3) { M3 = v.w; m3 = (1u << k); } else if (v.w == M3) { m3 |= (1u << k); }
    }
    smask[s][tid] = make_uint4(m0, m1, m2, m3);
    smaxv[s][tid] = make_float4(M0, M1, M2, M3);

    __syncthreads();

    // Global column maxes = max over the 16 segment-end running maxes.
    float4 Mg = smaxv[0][tid];
    #pragma unroll
    for (int ss = 1; ss < SEG; ++ss) {
        const float4 t = smaxv[ss][tid];
        Mg.x = fmaxf(Mg.x, t.x);
        Mg.y = fmaxf(Mg.y, t.y);
        Mg.z = fmaxf(Mg.z, t.z);
        Mg.w = fmaxf(Mg.w, t.w);
    }

    // This thread's zero-stores must complete before its sparse 1-overwrites
    // (same addresses; global writes may complete out of order).
    asm volatile("s_waitcnt vmcnt(0)" ::: "memory");

    // ---- Pass 2: each wave evaluates candidates in its own segment
    // (channels where v == column max). Expected ~1 candidate per column.
    const bool has_u = (i > 0), has_d = (i < Hn - 1);

    #pragma unroll
    for (int col = 0; col < 4; ++col) {
        const int j = j0 + col;
        const float Mgc = (col == 0) ? Mg.x : (col == 1) ? Mg.y : (col == 2) ? Mg.z : Mg.w;
        const float Msc = (col == 0) ? M0   : (col == 1) ? M1   : (col == 2) ? M2   : M3;
        if (Msc != Mgc) continue;                 // this segment's max is stale
        const bool has_l = (j > 0), has_r = (j < Wn - 1);

        uint32_t m = (col == 0) ? m0 : (col == 1) ? m1 : (col == 2) ? m2 : m3;
        while (m) {
            const int k = __ffs(m) - 1;
            m &= (m - 1u);
            const int c = s * CPS + k;
            const size_t p = base + (size_t)col + (size_t)c * (size_t)CH;
            const float v = Mgc;                  // == in[p] by construction

            // 3x3 neighborhood; OOB -> 0 for the Hessian (zero-pad), and the
            // local-max test skips OOB neighbors (-inf pad semantics).
            const float nu  = has_u ? in[p - Wn] : 0.0f;
            const float nd  = has_d ? in[p + Wn] : 0.0f;
            const float nl  = has_l ? in[p - 1]  : 0.0f;
            const float nr  = has_r ? in[p + 1]  : 0.0f;
            const float nul = (has_u && has_l) ? in[p - Wn - 1] : 0.0f;
            const float nur = (has_u && has_r) ? in[p - Wn + 1] : 0.0f;
            const float ndl = (has_d && has_l) ? in[p + Wn - 1] : 0.0f;
            const float ndr = (has_d && has_r) ? in[p + Wn + 1] : 0.0f;

            const bool lm =
                (!has_u || v >= nu) && (!has_d || v >= nd) &&
                (!has_l || v >= nl) && (!has_r || v >= nr) &&
                (!(has_u && has_l) || v >= nul) &&
                (!(has_u && has_r) || v >= nur) &&
                (!(has_d && has_l) || v >= ndl) &&
                (!(has_d && has_r) || v >= ndr);

            if (lm) {
                // Hessian edge test, f32 ops matching numpy rounding.
                // __fmul_rn blocks fma contraction (det sign / ratio must
                // round exactly like separate-mul-then-sub).
                const float dii = (nu + nd) - 2.0f * v;
                const float djj = (nl + nr) - 2.0f * v;
                const float dij = 0.25f * (((nul - nur) - ndl) + ndr);
                const float det = __fmul_rn(dii, djj) - __fmul_rn(dij, dij);
                const float tr  = dii + djj;
                const float ratio = __fmul_rn(tr, tr) / det;   // inf/nan ok if det<=0
                if (det > 0.0f && ratio <= 7.2f) {             // 36/5
                    out[p] = 1;
                }
            }
        }
    }
}

} // namespace

extern "C" void kernel_launch(void* const* d_in, const int* in_sizes, int n_in,
                              void* d_out, int out_size, void* d_ws, size_t ws_size,
                              hipStream_t stream) {
    const float* in = (const float*)d_in[0];
    int* out = (int*)d_out;
    (void)in_sizes; (void)n_in; (void)out_size; (void)d_ws; (void)ws_size;

    dim3 grid(1, Hn, Bn);   // 192 x 2 = 384 blocks x 16 waves (2 blocks/CU fit)
    dim3 block(1024);
    hipLaunchKernelGGL(hard_detect_kernel, grid, block, 0, stream, in, out);
}

// Round 10
// 67.358 us; speedup vs baseline: 1.0999x; 1.0999x over previous
//
#include <hip/hip_runtime.h>
#include <cstdint>
#include <cstddef>

// HardDetectionModule: per-element detect = is_depth_wise_max & is_local_max & is_not_edge
// batch: (B=2, C=512, H=192, W=256) float32, row-major.
// Output: same shape, int32 0/1 (reference returns bool -> harness reads int32).
//
// R9 post-mortem: float4 with 1024-thread blocks regressed (74 us) because
// grid=384 on 256 CUs -> occupancy 35%. R10: keep R6's proven geometry
// (768 x 512-thread blocks, 3 blocks/CU, occupancy ~65%) and get 16B/lane
// via HALF-WAVE segments: lane=tid&31 owns 4 columns, s=tid>>5 owns a
// 32-channel segment. Same bytes, half the vmem instructions of R6.

namespace {

constexpr int Bn = 2;
constexpr int Cn = 512;
constexpr int Hn = 192;
constexpr int Wn = 256;
constexpr int CH  = Hn * Wn;         // channel stride in elements (49152)
constexpr int SEG = 16;              // half-wave segments per column
constexpr int CPS = Cn / SEG;        // 32 channels per segment

typedef float f32x4 __attribute__((ext_vector_type(4)));
typedef int   i32x4 __attribute__((ext_vector_type(4)));

__global__ __launch_bounds__(512)
void hard_detect_kernel(const float* __restrict__ in, int* __restrict__ out) {
    const int lane = threadIdx.x & 31;           // column-group lane 0..31
    const int s    = threadIdx.x >> 5;           // segment (half-wave) 0..15
    const int j0   = blockIdx.x * 128 + lane * 4; // first of this lane's 4 cols
    const int i    = blockIdx.y;                 // 0..191
    const int b    = blockIdx.z;                 // 0..1

    // [segment][lane], 16B per lane.
    __shared__ uint4  smask[SEG][32];
    __shared__ float4 smaxv[SEG][32];

    // element index of (b, c=0, i, j0)
    const size_t base = ((size_t)b * Cn * Hn + (size_t)i) * Wn + (size_t)j0;

    // ---- Pass 1: each half-wave streams its 32-channel segment, 4 cols/lane.
    //  - per-column running max M0..M3
    //  - zero the output (mandatory full write; doubles as init), 16B NT store
    //  - bitmask of "v == running max" per column (mask resets when a strictly
    //    larger value appears) + running max at segment end. A segment's mask
    //    is valid iff its end-max equals the final column max; surviving bits
    //    mark exactly the channels equal to it (ties exact).
    float M0 = -__builtin_inff(), M1 = M0, M2 = M0, M3 = M0;
    uint32_t m0 = 0u, m1 = 0u, m2 = 0u, m3 = 0u;
    #pragma unroll
    for (int k = 0; k < CPS; ++k) {
        const int c = s * CPS + k;
        const size_t idx = base + (size_t)c * (size_t)CH;
        const f32x4 v = *reinterpret_cast<const f32x4*>(&in[idx]);
        const i32x4 z = {0, 0, 0, 0};
        __builtin_nontemporal_store(z, reinterpret_cast<i32x4*>(&out[idx]));
        if (v.x > M0) { M0 = v.x; m0 = (1u << k); } else if (v.x == M0) { m0 |= (1u << k); }
        if (v.y > M1) { M1 = v.y; m1 = (1u << k); } else if (v.y == M1) { m1 |= (1u << k); }
        if (v.z > M2) { M2 = v.z; m2 = (1u << k); } else if (v.z == M2) { m2 |= (1u << k); }
        if (v.w > M3) { M3 = v.w; m3 = (1u << k); } else if (v.w == M3) { m3 |= (1u << k); }
    }
    smask[s][lane] = make_uint4(m0, m1, m2, m3);
    smaxv[s][lane] = make_float4(M0, M1, M2, M3);

    __syncthreads();

    // Global column maxes = max over the 16 segment-end running maxes.
    float4 Mg = smaxv[0][lane];
    #pragma unroll
    for (int ss = 1; ss < SEG; ++ss) {
        const float4 t = smaxv[ss][lane];
        Mg.x = fmaxf(Mg.x, t.x);
        Mg.y = fmaxf(Mg.y, t.y);
        Mg.z = fmaxf(Mg.z, t.z);
        Mg.w = fmaxf(Mg.w, t.w);
    }

    // This thread's zero-stores must complete before its sparse 1-overwrites
    // (same addresses; global writes may complete out of order).
    asm volatile("s_waitcnt vmcnt(0)" ::: "memory");

    // ---- Pass 2: each half-wave evaluates candidates in its own segment
    // (channels where v == column max). Expected ~1 candidate per column.
    const bool has_u = (i > 0), has_d = (i < Hn - 1);

    #pragma unroll
    for (int col = 0; col < 4; ++col) {
        const int j = j0 + col;
        const float Mgc = (col == 0) ? Mg.x : (col == 1) ? Mg.y : (col == 2) ? Mg.z : Mg.w;
        const float Msc = (col == 0) ? M0   : (col == 1) ? M1   : (col == 2) ? M2   : M3;
        if (Msc != Mgc) continue;                 // this segment's max is stale
        const bool has_l = (j > 0), has_r = (j < Wn - 1);

        uint32_t m = (col == 0) ? m0 : (col == 1) ? m1 : (col == 2) ? m2 : m3;
        while (m) {
            const int k = __ffs(m) - 1;
            m &= (m - 1u);
            const int c = s * CPS + k;
            const size_t p = base + (size_t)col + (size_t)c * (size_t)CH;
            const float v = Mgc;                  // == in[p] by construction

            // 3x3 neighborhood; OOB -> 0 for the Hessian (zero-pad), and the
            // local-max test skips OOB neighbors (-inf pad semantics).
            const float nu  = has_u ? in[p - Wn] : 0.0f;
            const float nd  = has_d ? in[p + Wn] : 0.0f;
            const float nl  = has_l ? in[p - 1]  : 0.0f;
            const float nr  = has_r ? in[p + 1]  : 0.0f;
            const float nul = (has_u && has_l) ? in[p - Wn - 1] : 0.0f;
            const float nur = (has_u && has_r) ? in[p - Wn + 1] : 0.0f;
            const float ndl = (has_d && has_l) ? in[p + Wn - 1] : 0.0f;
            const float ndr = (has_d && has_r) ? in[p + Wn + 1] : 0.0f;

            const bool lm =
                (!has_u || v >= nu) && (!has_d || v >= nd) &&
                (!has_l || v >= nl) && (!has_r || v >= nr) &&
                (!(has_u && has_l) || v >= nul) &&
                (!(has_u && has_r) || v >= nur) &&
                (!(has_d && has_l) || v >= ndl) &&
                (!(has_d && has_r) || v >= ndr);

            if (lm) {
                // Hessian edge test, f32 ops matching numpy rounding.
                // __fmul_rn blocks fma contraction (det sign / ratio must
                // round exactly like separate-mul-then-sub).
                const float dii = (nu + nd) - 2.0f * v;
                const float djj = (nl + nr) - 2.0f * v;
                const float dij = 0.25f * (((nul - nur) - ndl) + ndr);
                const float det = __fmul_rn(dii, djj) - __fmul_rn(dij, dij);
                const float tr  = dii + djj;
                const float ratio = __fmul_rn(tr, tr) / det;   // inf/nan ok if det<=0
                if (det > 0.0f && ratio <= 7.2f) {             // 36/5
                    out[p] = 1;
                }
            }
        }
    }
}

} // namespace

extern "C" void kernel_launch(void* const* d_in, const int* in_sizes, int n_in,
                              void* d_out, int out_size, void* d_ws, size_t ws_size,
                              hipStream_t stream) {
    const float* in = (const float*)d_in[0];
    int* out = (int*)d_out;
    (void)in_sizes; (void)n_in; (void)out_size; (void)d_ws; (void)ws_size;

    dim3 grid(2, Hn, Bn);   // 2 x 192 x 2 = 768 blocks x 8 waves (3 blocks/CU)
    dim3 block(512);
    hipLaunchKernelGGL(hard_detect_kernel, grid, block, 0, stream, in, out);
}